// Round 6
// baseline (284.632 us; speedup 1.0000x reference)
//
#include <hip/hip_runtime.h>

// ============================================================================
// ROUND 6 = DIAGNOSTIC BUILD.  Base: the 217.3us champion (R0) EXACTLY, plus
// 3 replicated compute passes (CSE-proof inputs, asm keepalive, no LDS/store
// side effects) to push kernel dur above the ~122us harness fills so the
// kernel's own rocprof row finally appears in the top-5 table.
// Expected: dur_us ~250 (worse than champion, intentionally).  The readout:
// VALUBusy / Occupancy / WRITE_SIZE / FETCH_SIZE / LDS_BANK_CONFLICT of the
// kest_kernel dispatch row.  Champion source is this file minus the DIAG
// block and this comment.
// ============================================================================

#define KK 49
#define BLK 256
#define PPW 32                 // pixels per wave (TPP=2)
#define PPB 128                // pixels per block (4 waves)
#define WFL (PPW * KK)         // floats per wave slice = 1568
#define WF4 (WFL / 4)          // float4 per wave slice = 392

typedef float v2f __attribute__((ext_vector_type(2)));

static __device__ __forceinline__ v2f v2bc(float s) { v2f r; r.x = s; r.y = s; return r; }

// Catmull-Rom a=-0.5, branchless, packed 2-wide:
// w = 0.5*t2^3 - 0.5*t2^2 + t1^2 - 2*t1^3,  t2=max(0,2-|x|), t1=max(0,1-|x|)
static __device__ __forceinline__ v2f cubic2(v2f x) {
    v2f ax = __builtin_elementwise_abs(x);
    v2f t2 = __builtin_elementwise_max(v2bc(2.0f) - ax, v2bc(0.0f));
    v2f t1 = __builtin_elementwise_max(v2bc(1.0f) - ax, v2bc(0.0f));
    v2f r  = (t2 * t2) * __builtin_elementwise_fma(v2bc(0.5f), t2, v2bc(-0.5f));
    return __builtin_elementwise_fma(t1 * t1,
              __builtin_elementwise_fma(v2bc(-2.0f), t1, v2bc(1.0f)), r);
}

__global__ __launch_bounds__(BLK, 6) void kest_kernel(
    const float* __restrict__ m,
    const float* __restrict__ grid,
    const int*   __restrict__ Wp,
    const int*   __restrict__ yi,
    float*       __restrict__ out,
    int N)
{
    __shared__ __align__(16) float lds[4 * WFL];   // 25088 B -> 6 blocks/CU

    const int tid   = threadIdx.x;
    const int wv_   = tid >> 6;          // wave id 0..3
    const int lane  = tid & 63;
    const int pixW  = lane >> 1;         // pixel-in-wave 0..31
    const int sub   = lane & 1;          // which half of the 49 weights
    const int blockBase = blockIdx.x * PPB;
    float* ldsW = &lds[wv_ * WFL];       // wave-private slice: NO barrier needed

    // ---- setup: lanes 0..31 each compute coeffs for pixel (waveBase+lane) ----
    float Axx = 0.f, Axy = 0.f, Ayx = 0.f, Ayy = 0.f, fxc = 0.f, fyc = 0.f;
    if (lane < 32) {
        const int p = blockBase + wv_ * PPW + lane;
        if (p < N) {
            const float m00 = m[0], m01 = m[1], m02 = m[2];
            const float m10 = m[3], m11 = m[4], m12 = m[5];
            const float m20 = m[6], m21 = m[7], m22 = m[8];
            const int   W   = Wp[0];

            const int j = yi[p];
            int yyI, xxI;
            if ((W & (W - 1)) == 0) {            // uniform branch (W=1024)
                yyI = j >> (__ffs(W) - 1);
                xxI = j & (W - 1);
            } else {
                yyI = j / W;
                xxI = j - yyI * W;
            }
            const float xx = (float)xxI, yy = (float)yyI;

            const float X0 = m00 * xx + m01 * yy + m02;
            const float Y0 = m10 * xx + m11 * yy + m12;
            const float Z0 = m20 * xx + m21 * yy + m22;

            // stable difference-of-quotients: du (eps_y=±0.5), dv (eps_x=±0.5)
            const float izy = __builtin_amdgcn_rcpf(Z0 * Z0 - 0.25f * m21 * m21);
            float du0 = (m01 * Z0 - m21 * X0) * izy;
            float du1 = (m11 * Z0 - m21 * Y0) * izy;
            const float izx = __builtin_amdgcn_rcpf(Z0 * Z0 - 0.25f * m20 * m20);
            float dv0 = (m00 * Z0 - m20 * X0) * izx;
            float dv1 = (m10 * Z0 - m20 * Y0) * izx;

            const float d2u = du0 * du0 + du1 * du1;
            const float rlu = __builtin_amdgcn_rsqf(d2u);
            float len_du = d2u * rlu;
            if (len_du < 1.0f) { du0 *= rlu; du1 *= rlu; len_du = 1.0f; }
            const float d2v = dv0 * dv0 + dv1 * dv1;
            const float rlv = __builtin_amdgcn_rsqf(d2v);
            float len_dv = d2v * rlv;
            if (len_dv < 1.0f) { dv0 *= rlv; dv1 *= rlv; len_dv = 1.0f; }

            const float det  = du0 * dv1 - du1 * dv0;
            const float r_du = __builtin_amdgcn_rcpf(len_du * det);
            const float r_dv = __builtin_amdgcn_rcpf(len_dv * det);

            const float p1 = du0 * dv1, p2 = du1 * dv0;
            Axx = p1 * r_du - p2 * r_dv;
            Axy = du0 * du1 * (r_dv - r_du);
            Ayx = dv0 * dv1 * (r_du - r_dv);
            Ayy = p1 * r_dv - p2 * r_du;

            const float px = grid[p]     + 0.5f;
            const float py = grid[N + p] + 0.5f;
            fxc = (px - __builtin_floorf(px)) + 2.5f;
            fyc = (py - __builtin_floorf(py)) + 2.5f;
        }
    }
    // distribute coeffs: lane needs values from setup-lane pixW (0..31)
    Axx = __shfl(Axx, pixW); Axy = __shfl(Axy, pixW);
    Ayx = __shfl(Ayx, pixW); Ayy = __shfl(Ayy, pixW);
    fxc = __shfl(fxc, pixW); fyc = __shfl(fyc, pixW);

    const int i = blockBase + wv_ * PPW + pixW;   // this lane's pixel
    if (i < N) {
        const float subf = (float)sub;
        const v2f subf2 = v2bc(subf);
        const v2f Axx2 = v2bc(Axx), Axy2 = v2bc(Axy);
        const v2f Ayx2 = v2bc(Ayx), Ayy2 = v2bc(Ayy);

        // ==================== DIAG: 3 replicated compute passes =============
        // Distinct inputs (fxc+rep / fyc-rep) defeat CSE; wsd keepalive via
        // empty asm defeats DCE (rule #17).  No LDS writes, no stores, and
        // wsd dies before the real loop so peak VGPR pressure is unchanged.
        {
            v2f wsd = v2bc(0.0f);
#pragma unroll
            for (int rep = 1; rep <= 3; ++rep) {
                const float fxr = fxc + (float)rep;
                const float fyr = fyc - (float)rep;
#pragma unroll
                for (int j = 0; j < 13; ++j) {
                    const int q0 = 4 * j, q1 = 4 * j + 2;
                    const float cx0 = (float)(q0 % 7), cx1 = (float)(q1 % 7);
                    const float dx0 = (float)((q0 + 1) % 7 - q0 % 7);
                    const float dx1 = (float)((q1 + 1) % 7 - q1 % 7);
                    const float ry0 = (float)(q0 / 7), ry1 = (float)(q1 / 7);
                    const float dy0 = (float)((q0 + 1) / 7 - q0 / 7);
                    const float dy1 = (float)((q1 + 1) / 7 - q1 / 7);

                    v2f wxv; wxv.x = fxr - cx0; wxv.y = fxr - cx1;
                    v2f dxv; dxv.x = -dx0;      dxv.y = -dx1;
                    wxv = __builtin_elementwise_fma(subf2, dxv, wxv);
                    v2f wyv; wyv.x = fyr - ry0; wyv.y = fyr - ry1;
                    v2f dyv; dyv.x = -dy0;      dyv.y = -dy1;
                    wyv = __builtin_elementwise_fma(subf2, dyv, wyv);

                    v2f x2 = __builtin_elementwise_fma(Axx2, wxv, Axy2 * wyv);
                    v2f y2 = __builtin_elementwise_fma(Ayx2, wxv, Ayy2 * wyv);
                    v2f w2 = cubic2(x2) * cubic2(y2);
                    if (j == 12) {
                        w2.x *= (1.0f - subf);
                        w2.y  = 0.0f;
                    }
                    wsd += w2;
                }
            }
            asm volatile("" :: "v"(wsd.x), "v"(wsd.y));   // keepalive, no DCE
        }
        // ==================== end DIAG ======================================

        // weights q = 4j + 2e + sub  (e = vector half), j = 0..12
        v2f wv2[13];
        v2f ws2 = v2bc(0.0f);
#pragma unroll
        for (int j = 0; j < 13; ++j) {
            const int q0 = 4 * j, q1 = 4 * j + 2;
            const float cx0 = (float)(q0 % 7), cx1 = (float)(q1 % 7);
            const float dx0 = (float)((q0 + 1) % 7 - q0 % 7);
            const float dx1 = (float)((q1 + 1) % 7 - q1 % 7);
            const float ry0 = (float)(q0 / 7), ry1 = (float)(q1 / 7);
            const float dy0 = (float)((q0 + 1) / 7 - q0 / 7);
            const float dy1 = (float)((q1 + 1) / 7 - q1 / 7);

            v2f wxv; wxv.x = fxc - cx0; wxv.y = fxc - cx1;
            v2f dxv; dxv.x = -dx0;      dxv.y = -dx1;
            wxv = __builtin_elementwise_fma(subf2, dxv, wxv);
            v2f wyv; wyv.x = fyc - ry0; wyv.y = fyc - ry1;
            v2f dyv; dyv.x = -dy0;      dyv.y = -dy1;
            wyv = __builtin_elementwise_fma(subf2, dyv, wyv);

            v2f x2 = __builtin_elementwise_fma(Axx2, wxv, Axy2 * wyv);
            v2f y2 = __builtin_elementwise_fma(Ayx2, wxv, Ayy2 * wyv);
            v2f w2 = cubic2(x2) * cubic2(y2);
            if (j == 12) {                 // q = 48+sub / 50+sub: mask invalid
                w2.x *= (1.0f - subf);
                w2.y  = 0.0f;
            }
            ws2 += w2;
            wv2[j] = w2;
        }
        float wsum = ws2.x + ws2.y;
        wsum += __shfl_xor(wsum, 1);       // combine the pixel's two lanes
        const float rs = __builtin_amdgcn_rcpf(wsum);
        const v2f rs2 = v2bc(rs);

        // LDS write: addr = pixW*49 + 4j + 2e + sub; banks 17*pixW+sub mod 32
        // -> at most 2-way aliasing (free)
        float* base = &ldsW[pixW * KK + sub];
#pragma unroll
        for (int j = 0; j < 13; ++j) {
            const v2f v = wv2[j] * rs2;
            if (j < 12) {
                base[4 * j]     = v.x;
                base[4 * j + 2] = v.y;
            } else if (sub == 0) {
                base[48] = v.x;            // q=48 only; q>=49 would corrupt
            }
        }
    }

    // ---- wave-private drain, no barrier: compiler's lgkmcnt wait suffices ----
    const long long dstF4 = (long long)blockIdx.x * (PPB * KK / 4) + wv_ * WF4;
    if (blockBase + PPB <= N) {            // uniform fast path: block fully valid
        const float4* src = (const float4*)ldsW;
        float4* dst = (float4*)out + dstF4;
#pragma unroll
        for (int k = 0; k < 7; ++k) {
            const int t = lane + 64 * k;
            if (t < WF4) dst[t] = src[t];  // k<6 always; k=6: lanes 0..7
        }
    } else {                               // tail block: scalar, bounds-checked
        const float* s = (const float*)ldsW;
        const long long baseF = dstF4 * 4;
        const long long limF  = (long long)N * KK;
        for (int t = lane; t < WFL; t += 64)
            if (baseF + t < limF) out[baseF + t] = s[t];
    }
}

extern "C" void kernel_launch(void* const* d_in, const int* in_sizes, int n_in,
                              void* d_out, int out_size, void* d_ws, size_t ws_size,
                              hipStream_t stream) {
    // inputs: m_inverse(9 f32), grid(2N f32), H(1 i32), W(1 i32), yi(N i32)
    const float* m    = (const float*)d_in[0];
    const float* grid = (const float*)d_in[1];
    const int*   Wp   = (const int*)d_in[3];
    const int*   yi   = (const int*)d_in[4];
    float*       out  = (float*)d_out;
    const int N = in_sizes[4];

    const int blocks = (N + PPB - 1) / PPB;
    kest_kernel<<<blocks, BLK, 0, stream>>>(m, grid, Wp, yi, out, N);
}

// Round 7
// 224.075 us; speedup vs baseline: 1.2702x; 1.2702x over previous
//
#include <hip/hip_runtime.h>

#define KK 49
#define BLK 256
#define PPW 32                 // pixels per wave (TPP=2)
#define PPB 128                // pixels per block (4 waves)
#define WFL (PPW * KK)         // floats per wave slice = 1568
#define WF4 (WFL / 4)          // float4 per wave slice = 392

typedef float v2f __attribute__((ext_vector_type(2)));

static __device__ __forceinline__ v2f v2bc(float s) { v2f r; r.x = s; r.y = s; return r; }

// ---- forced VOP3P packed-f32 math (R6 evidence: hipcc scalarizes v2f ops;
// VALUBusy 88% with ~2.2x the packed-issue estimate).  v_pk_*_f32 does 2
// f32 lanes per 2-cycle wave64 issue slot = 2x VALU throughput. ----
#define PKFMA(D,A,B,C) asm("v_pk_fma_f32 %0, %1, %2, %3" : "=v"(D) : "v"(A), "v"(B), "v"(C))
#define PKMUL(D,A,B)   asm("v_pk_mul_f32 %0, %1, %2"     : "=v"(D) : "v"(A), "v"(B))
#define PKADD(D,A,B)   asm("v_pk_add_f32 %0, %1, %2"     : "=v"(D) : "v"(A), "v"(B))

// Catmull-Rom a=-0.5 on a packed pair.  t2=max(2-|x|,0), t1=max(t2-1,0),
// w = t2^2*0.5*(t2-1) + t1^2*(1-2*t1).  Only the two clamps are scalar
// (no v_pk_max_f32 exists); all arithmetic is VOP3P.
static __device__ __forceinline__ v2f cubic2pk(v2f x, v2f KM1, v2f K2, v2f KM2,
                                               v2f K1, v2f KH) {
    v2f ax; ax.x = __builtin_fabsf(x.x); ax.y = __builtin_fabsf(x.y);
    v2f t2; PKFMA(t2, ax, KM1, K2);               // 2-|x|
    t2.x = __builtin_fmaxf(t2.x, 0.0f);
    t2.y = __builtin_fmaxf(t2.y, 0.0f);
    v2f u;  PKADD(u, t2, KM1);                    // t2-1  (== 1-|x| clamped-shift)
    v2f h;  PKMUL(h, u, KH);                      // 0.5*(t2-1)
    v2f t1; t1.x = __builtin_fmaxf(u.x, 0.0f);
            t1.y = __builtin_fmaxf(u.y, 0.0f);
    v2f t2sq; PKMUL(t2sq, t2, t2);
    v2f r;    PKMUL(r, t2sq, h);                  // t2^2 * 0.5(t2-1)
    v2f g;    PKFMA(g, t1, KM2, K1);              // 1-2*t1
    v2f t1sq; PKMUL(t1sq, t1, t1);
    v2f res;  PKFMA(res, t1sq, g, r);
    return res;
}

__global__ __launch_bounds__(BLK, 6) void kest_kernel(
    const float* __restrict__ m,
    const float* __restrict__ grid,
    const int*   __restrict__ Wp,
    const int*   __restrict__ yi,
    float*       __restrict__ out,
    int N)
{
    __shared__ __align__(16) float lds[4 * WFL];   // 25088 B -> 6 blocks/CU

    const int tid   = threadIdx.x;
    const int wv_   = tid >> 6;          // wave id 0..3
    const int lane  = tid & 63;
    const int pixW  = lane >> 1;         // pixel-in-wave 0..31
    const int sub   = lane & 1;          // which half of the 49 weights
    const int blockBase = blockIdx.x * PPB;
    float* ldsW = &lds[wv_ * WFL];       // wave-private slice: NO barrier needed

    // ---- setup: lanes 0..31 each compute coeffs for pixel (waveBase+lane) ----
    float Axx = 0.f, Axy = 0.f, Ayx = 0.f, Ayy = 0.f, fxc = 0.f, fyc = 0.f;
    if (lane < 32) {
        const int p = blockBase + wv_ * PPW + lane;
        if (p < N) {
            const float m00 = m[0], m01 = m[1], m02 = m[2];
            const float m10 = m[3], m11 = m[4], m12 = m[5];
            const float m20 = m[6], m21 = m[7], m22 = m[8];
            const int   W   = Wp[0];

            const int j = yi[p];
            int yyI, xxI;
            if ((W & (W - 1)) == 0) {            // uniform branch (W=1024)
                yyI = j >> (__ffs(W) - 1);
                xxI = j & (W - 1);
            } else {
                yyI = j / W;
                xxI = j - yyI * W;
            }
            const float xx = (float)xxI, yy = (float)yyI;

            const float X0 = m00 * xx + m01 * yy + m02;
            const float Y0 = m10 * xx + m11 * yy + m12;
            const float Z0 = m20 * xx + m21 * yy + m22;

            // stable difference-of-quotients: du (eps_y=±0.5), dv (eps_x=±0.5)
            const float izy = __builtin_amdgcn_rcpf(Z0 * Z0 - 0.25f * m21 * m21);
            float du0 = (m01 * Z0 - m21 * X0) * izy;
            float du1 = (m11 * Z0 - m21 * Y0) * izy;
            const float izx = __builtin_amdgcn_rcpf(Z0 * Z0 - 0.25f * m20 * m20);
            float dv0 = (m00 * Z0 - m20 * X0) * izx;
            float dv1 = (m10 * Z0 - m20 * Y0) * izx;

            const float d2u = du0 * du0 + du1 * du1;
            const float rlu = __builtin_amdgcn_rsqf(d2u);
            float len_du = d2u * rlu;
            if (len_du < 1.0f) { du0 *= rlu; du1 *= rlu; len_du = 1.0f; }
            const float d2v = dv0 * dv0 + dv1 * dv1;
            const float rlv = __builtin_amdgcn_rsqf(d2v);
            float len_dv = d2v * rlv;
            if (len_dv < 1.0f) { dv0 *= rlv; dv1 *= rlv; len_dv = 1.0f; }

            const float det  = du0 * dv1 - du1 * dv0;
            const float r_du = __builtin_amdgcn_rcpf(len_du * det);
            const float r_dv = __builtin_amdgcn_rcpf(len_dv * det);

            const float p1 = du0 * dv1, p2 = du1 * dv0;
            Axx = p1 * r_du - p2 * r_dv;
            Axy = du0 * du1 * (r_dv - r_du);
            Ayx = dv0 * dv1 * (r_du - r_dv);
            Ayy = p1 * r_dv - p2 * r_du;

            const float px = grid[p]     + 0.5f;
            const float py = grid[N + p] + 0.5f;
            fxc = (px - __builtin_floorf(px)) + 2.5f;
            fyc = (py - __builtin_floorf(py)) + 2.5f;
        }
    }
    // distribute coeffs: lane needs values from setup-lane pixW (0..31)
    Axx = __shfl(Axx, pixW); Axy = __shfl(Axy, pixW);
    Ayx = __shfl(Ayx, pixW); Ayy = __shfl(Ayy, pixW);
    fxc = __shfl(fxc, pixW); fyc = __shfl(fyc, pixW);

    const int i = blockBase + wv_ * PPW + pixW;   // this lane's pixel
    if (i < N) {
        const float subf = (float)sub;
        const v2f Axx2 = v2bc(Axx), Axy2 = v2bc(Axy);
        const v2f Ayx2 = v2bc(Ayx), Ayy2 = v2bc(Ayy);

        // packed-math constants (held in register pairs for the asm chain)
        const v2f KM1 = v2bc(-1.0f), K2 = v2bc(2.0f), KM2 = v2bc(-2.0f);
        const v2f K1  = v2bc(1.0f),  KH = v2bc(0.5f);

        // Tap construction: q = 4j + 2e + sub.  wx = fxc - cx0(q') - sub*dx
        // with dx in {1,-6} compile-time per slot -> pick one of two bases:
        //   dx=+1: wx = (fxc - sub) - cx0        dx=-6: wx = (fxc + 6*sub) - cx0
        // One scalar sub per component instead of sub+fma.
        const float fx1 = fxc - subf;                       // x-base for dx=+1
        const float fx6 = __builtin_fmaf(6.0f, subf, fxc);  // x-base for dx=-6
        const float fy1 = fyc - subf;                       // y-base for dy=+1

        // weights q = 4j + 2e + sub  (e = vector half), j = 0..12
        v2f wv2[13];
        v2f ws2 = v2bc(0.0f);
#pragma unroll
        for (int j = 0; j < 13; ++j) {
            const int q0 = 4 * j, q1 = 4 * j + 2;
            const int cx0 = q0 % 7, cx1 = q1 % 7;
            const int dx0 = (q0 + 1) % 7 - cx0;   // +1 or -6, compile-time
            const int dx1 = (q1 + 1) % 7 - cx1;
            const int ry0 = q0 / 7, ry1 = q1 / 7;
            const int dy0 = (q0 + 1) / 7 - ry0;   // 0 or 1, compile-time
            const int dy1 = (q1 + 1) / 7 - ry1;

            v2f wxv, wyv;
            wxv.x = (dx0 == 1 ? fx1 : fx6) - (float)cx0;
            wxv.y = (dx1 == 1 ? fx1 : fx6) - (float)cx1;
            wyv.x = (dy0 == 0 ? fyc : fy1) - (float)ry0;
            wyv.y = (dy1 == 0 ? fyc : fy1) - (float)ry1;

            v2f tx; PKMUL(tx, Axy2, wyv);
            v2f x2; PKFMA(x2, Axx2, wxv, tx);
            v2f ty; PKMUL(ty, Ayy2, wyv);
            v2f y2; PKFMA(y2, Ayx2, wxv, ty);

            v2f cxv = cubic2pk(x2, KM1, K2, KM2, K1, KH);
            v2f cyv = cubic2pk(y2, KM1, K2, KM2, K1, KH);
            v2f w2; PKMUL(w2, cxv, cyv);
            if (j == 12) {                 // q = 48+sub / 50+sub: mask invalid
                w2.x *= (1.0f - subf);
                w2.y  = 0.0f;
            }
            PKADD(ws2, ws2, w2);
            wv2[j] = w2;
        }
        float wsum = ws2.x + ws2.y;
        wsum += __shfl_xor(wsum, 1);       // combine the pixel's two lanes
        const float rs = __builtin_amdgcn_rcpf(wsum);
        const v2f rs2 = v2bc(rs);

        // LDS write: addr = pixW*49 + 4j + 2e + sub; banks 17*pixW+sub mod 32
        // -> at most 2-way aliasing (free)
        float* base = &ldsW[pixW * KK + sub];
#pragma unroll
        for (int j = 0; j < 13; ++j) {
            v2f v; PKMUL(v, wv2[j], rs2);
            if (j < 12) {
                base[4 * j]     = v.x;
                base[4 * j + 2] = v.y;
            } else if (sub == 0) {
                base[48] = v.x;            // q=48 only; q>=49 would corrupt
            }
        }
    }

    // ---- wave-private drain, no barrier: compiler's lgkmcnt wait suffices ----
    const long long dstF4 = (long long)blockIdx.x * (PPB * KK / 4) + wv_ * WF4;
    if (blockBase + PPB <= N) {            // uniform fast path: block fully valid
        const float4* src = (const float4*)ldsW;
        float4* dst = (float4*)out + dstF4;
#pragma unroll
        for (int k = 0; k < 7; ++k) {
            const int t = lane + 64 * k;
            if (t < WF4) dst[t] = src[t];  // k<6 always; k=6: lanes 0..7
        }
    } else {                               // tail block: scalar, bounds-checked
        const float* s = (const float*)ldsW;
        const long long baseF = dstF4 * 4;
        const long long limF  = (long long)N * KK;
        for (int t = lane; t < WFL; t += 64)
            if (baseF + t < limF) out[baseF + t] = s[t];
    }
}

extern "C" void kernel_launch(void* const* d_in, const int* in_sizes, int n_in,
                              void* d_out, int out_size, void* d_ws, size_t ws_size,
                              hipStream_t stream) {
    // inputs: m_inverse(9 f32), grid(2N f32), H(1 i32), W(1 i32), yi(N i32)
    const float* m    = (const float*)d_in[0];
    const float* grid = (const float*)d_in[1];
    const int*   Wp   = (const int*)d_in[3];
    const int*   yi   = (const int*)d_in[4];
    float*       out  = (float*)d_out;
    const int N = in_sizes[4];

    const int blocks = (N + PPB - 1) / PPB;
    kest_kernel<<<blocks, BLK, 0, stream>>>(m, grid, Wp, yi, out, N);
}

// Round 8
// 219.820 us; speedup vs baseline: 1.2948x; 1.0194x over previous
//
#include <hip/hip_runtime.h>

#define KK 49
#define BLK 256
#define PPW 32                 // pixels per wave (TPP=2)
#define PPB 128                // pixels per block (4 waves)
#define WFL (PPW * KK)         // floats per wave slice = 1568
#define WF4 (WFL / 4)          // float4 per wave slice = 392

// Catmull-Rom a=-0.5 via range-selected Horner, 9 VALU ops:
//   t = min(|x|,2);  s = t<1
//   P1 = 1.5t^3 - 2.5t^2 + 1        (s)
//   P2 = -0.5t^3 + 2.5t^2 - 4t + 2  (!s; P2(2)=0 handles |x|>=2 exactly)
// min(1) + cmp(1) + 4 cndmask + 3 fma = 9 ops, vs 10-11 for the max-chain.
static __device__ __forceinline__ float cubicH(float x) {
    const float t  = __builtin_fminf(__builtin_fabsf(x), 2.0f);
    const bool  s  = t < 1.0f;
    const float c3 = s ?  1.5f : -0.5f;
    const float c2 = s ? -2.5f :  2.5f;
    const float c1 = s ?  0.0f : -4.0f;
    const float c0 = s ?  1.0f :  2.0f;
    return __builtin_fmaf(__builtin_fmaf(__builtin_fmaf(c3, t, c2), t, c1), t, c0);
}

__global__ __launch_bounds__(BLK, 6) void kest_kernel(
    const float* __restrict__ m,
    const float* __restrict__ grid,
    const int*   __restrict__ Wp,
    const int*   __restrict__ yi,
    float*       __restrict__ out,
    int N)
{
    __shared__ __align__(16) float lds[4 * WFL];   // 25088 B -> 6 blocks/CU

    const int tid   = threadIdx.x;
    const int wv_   = tid >> 6;          // wave id 0..3
    const int lane  = tid & 63;
    const int pixW  = lane >> 1;         // pixel-in-wave 0..31
    const int sub   = lane & 1;          // which half of the 49 weights
    const int blockBase = blockIdx.x * PPB;
    float* ldsW = &lds[wv_ * WFL];       // wave-private slice: NO barrier needed

    // ---- setup: lanes 0..31 each compute coeffs for pixel (waveBase+lane) ----
    float Axx = 0.f, Axy = 0.f, Ayx = 0.f, Ayy = 0.f, fxc = 0.f, fyc = 0.f;
    if (lane < 32) {
        const int p = blockBase + wv_ * PPW + lane;
        if (p < N) {
            const float m00 = m[0], m01 = m[1], m02 = m[2];
            const float m10 = m[3], m11 = m[4], m12 = m[5];
            const float m20 = m[6], m21 = m[7], m22 = m[8];
            const int   W   = Wp[0];

            const int j = yi[p];
            int yyI, xxI;
            if ((W & (W - 1)) == 0) {            // uniform branch (W=1024)
                yyI = j >> (__ffs(W) - 1);
                xxI = j & (W - 1);
            } else {
                yyI = j / W;
                xxI = j - yyI * W;
            }
            const float xx = (float)xxI, yy = (float)yyI;

            const float X0 = m00 * xx + m01 * yy + m02;
            const float Y0 = m10 * xx + m11 * yy + m12;
            const float Z0 = m20 * xx + m21 * yy + m22;

            // stable difference-of-quotients: du (eps_y=±0.5), dv (eps_x=±0.5)
            const float izy = __builtin_amdgcn_rcpf(Z0 * Z0 - 0.25f * m21 * m21);
            float du0 = (m01 * Z0 - m21 * X0) * izy;
            float du1 = (m11 * Z0 - m21 * Y0) * izy;
            const float izx = __builtin_amdgcn_rcpf(Z0 * Z0 - 0.25f * m20 * m20);
            float dv0 = (m00 * Z0 - m20 * X0) * izx;
            float dv1 = (m10 * Z0 - m20 * Y0) * izx;

            const float d2u = du0 * du0 + du1 * du1;
            const float rlu = __builtin_amdgcn_rsqf(d2u);
            float len_du = d2u * rlu;
            if (len_du < 1.0f) { du0 *= rlu; du1 *= rlu; len_du = 1.0f; }
            const float d2v = dv0 * dv0 + dv1 * dv1;
            const float rlv = __builtin_amdgcn_rsqf(d2v);
            float len_dv = d2v * rlv;
            if (len_dv < 1.0f) { dv0 *= rlv; dv1 *= rlv; len_dv = 1.0f; }

            const float det  = du0 * dv1 - du1 * dv0;
            const float r_du = __builtin_amdgcn_rcpf(len_du * det);
            const float r_dv = __builtin_amdgcn_rcpf(len_dv * det);

            const float p1 = du0 * dv1, p2 = du1 * dv0;
            Axx = p1 * r_du - p2 * r_dv;
            Axy = du0 * du1 * (r_dv - r_du);
            Ayx = dv0 * dv1 * (r_du - r_dv);
            Ayy = p1 * r_dv - p2 * r_du;

            const float px = grid[p]     + 0.5f;
            const float py = grid[N + p] + 0.5f;
            fxc = (px - __builtin_floorf(px)) + 2.5f;
            fyc = (py - __builtin_floorf(py)) + 2.5f;
        }
    }
    // distribute coeffs: lane needs values from setup-lane pixW (0..31)
    Axx = __shfl(Axx, pixW); Axy = __shfl(Axy, pixW);
    Ayx = __shfl(Ayx, pixW); Ayy = __shfl(Ayy, pixW);
    fxc = __shfl(fxc, pixW); fyc = __shfl(fyc, pixW);

    const int i = blockBase + wv_ * PPW + pixW;   // this lane's pixel
    if (i < N) {
        const float subf = (float)sub;

        // Tap construction (R7 trick, proven correct there): q = qb + sub with
        // qb = 4j+2e compile-time.  cx(q) = cx(qb) + sub*dx, dx in {1,-6};
        // ry(q) = ry(qb) + sub*dy, dy in {0,1} -- all compile-time, so wx/wy
        // are ONE sub each from a precomputed sub-folded base:
        const float fx1 = fxc - subf;                       // x-base for dx=+1
        const float fx6 = __builtin_fmaf(6.0f, subf, fxc);  // x-base for dx=-6
        const float fy1 = fyc - subf;                       // y-base for dy=+1

        float w0[13], w1[13];              // slot e=0 / e=1 weights (registers)
        float ws = 0.0f;
#pragma unroll
        for (int j = 0; j < 13; ++j) {
            // ---- slot e=0: qb = 4j ----
            {
                const int qb  = 4 * j;
                const int cxb = qb % 7,            ryb = qb / 7;
                const int dx  = (qb + 1) % 7 - cxb;          // 1 or -6
                const int dy  = (qb + 1) / 7 - ryb;          // 0 or 1
                const float wx = (dx == 1 ? fx1 : fx6) - (float)cxb;
                const float wy = (dy == 0 ? fyc : fy1) - (float)ryb;
                const float x_ = __builtin_fmaf(Axx, wx, Axy * wy);
                const float y_ = __builtin_fmaf(Ayx, wx, Ayy * wy);
                float w = cubicH(x_) * cubicH(y_);
                if (j == 12) w *= (1.0f - subf);   // q=48 valid only for sub=0
                w0[j] = w;
                ws += w;
            }
            // ---- slot e=1: qb = 4j+2 (j=12 -> q=50/51 invalid: skip) ----
            if (j < 12) {
                const int qb  = 4 * j + 2;
                const int cxb = qb % 7,            ryb = qb / 7;
                const int dx  = (qb + 1) % 7 - cxb;
                const int dy  = (qb + 1) / 7 - ryb;
                const float wx = (dx == 1 ? fx1 : fx6) - (float)cxb;
                const float wy = (dy == 0 ? fyc : fy1) - (float)ryb;
                const float x_ = __builtin_fmaf(Axx, wx, Axy * wy);
                const float y_ = __builtin_fmaf(Ayx, wx, Ayy * wy);
                const float w = cubicH(x_) * cubicH(y_);
                w1[j] = w;
                ws += w;
            } else {
                w1[j] = 0.0f;
            }
        }
        float wsum = ws + __shfl_xor(ws, 1);   // combine the pixel's two lanes
        const float rs = __builtin_amdgcn_rcpf(wsum);

        // LDS write: addr = pixW*49 + 4j + 2e + sub; banks 17*pixW+sub mod 32
        // -> at most 2-way aliasing (free)
        float* base = &ldsW[pixW * KK + sub];
#pragma unroll
        for (int j = 0; j < 13; ++j) {
            if (j < 12) {
                base[4 * j]     = w0[j] * rs;
                base[4 * j + 2] = w1[j] * rs;
            } else if (sub == 0) {
                base[48] = w0[12] * rs;        // q=48 only; q>=49 would corrupt
            }
        }
    }

    // ---- wave-private drain, no barrier: compiler's lgkmcnt wait suffices ----
    const long long dstF4 = (long long)blockIdx.x * (PPB * KK / 4) + wv_ * WF4;
    if (blockBase + PPB <= N) {            // uniform fast path: block fully valid
        const float4* src = (const float4*)ldsW;
        float4* dst = (float4*)out + dstF4;
#pragma unroll
        for (int k = 0; k < 7; ++k) {
            const int t = lane + 64 * k;
            if (t < WF4) dst[t] = src[t];  // k<6 always; k=6: lanes 0..7
        }
    } else {                               // tail block: scalar, bounds-checked
        const float* s = (const float*)ldsW;
        const long long baseF = dstF4 * 4;
        const long long limF  = (long long)N * KK;
        for (int t = lane; t < WFL; t += 64)
            if (baseF + t < limF) out[baseF + t] = s[t];
    }
}

extern "C" void kernel_launch(void* const* d_in, const int* in_sizes, int n_in,
                              void* d_out, int out_size, void* d_ws, size_t ws_size,
                              hipStream_t stream) {
    // inputs: m_inverse(9 f32), grid(2N f32), H(1 i32), W(1 i32), yi(N i32)
    const float* m    = (const float*)d_in[0];
    const float* grid = (const float*)d_in[1];
    const int*   Wp   = (const int*)d_in[3];
    const int*   yi   = (const int*)d_in[4];
    float*       out  = (float*)d_out;
    const int N = in_sizes[4];

    const int blocks = (N + PPB - 1) / PPB;
    kest_kernel<<<blocks, BLK, 0, stream>>>(m, grid, Wp, yi, out, N);
}